// Round 15
// baseline (290.015 us; speedup 1.0000x reference)
//
#include <hip/hip_runtime.h>

constexpr int NN = 100000;   // nodes (= 3125 * 32 exactly)
constexpr int NE = 1600000;  // edges
constexpr int DD = 64;       // channels
constexpr int NG = 256;      // graphs

constexpr int BKT_SHIFT = 8;                   // 256 nodes per bucket
constexpr int NBKT = (NN + 255) >> BKT_SHIFT;  // 391 buckets
constexpr int EPB = 4096;                      // edges per block (build kernels)
constexpr int NEB = (NE + EPB - 1) / EPB;      // 391 blocks
constexpr int CAP = 16384;                     // pair window per bucket (mean 4092)

using bf16x8 = __attribute__((ext_vector_type(8))) short;
using f32x4 = __attribute__((ext_vector_type(4))) float;

// ---------------------------------------------------------------------------
// bf16 helpers (manual, RNE)
// ---------------------------------------------------------------------------
__device__ __forceinline__ float b2f(unsigned short u) {
    union { unsigned int u; float f; } c;
    c.u = ((unsigned int)u) << 16;
    return c.f;
}
__device__ __forceinline__ unsigned short f2b(float f) {
    union { float f; unsigned int u; } c;
    c.f = f;
    unsigned int u = c.u + 0x7fff + ((c.u >> 16) & 1);
    return (unsigned short)(u >> 16);
}
__device__ __forceinline__ float lo16(unsigned int u) {
    union { unsigned int u; float f; } c;
    c.u = u << 16;
    return c.f;
}
__device__ __forceinline__ float hi16(unsigned int u) {
    union { unsigned int u; float f; } c;
    c.u = u & 0xffff0000u;
    return c.f;
}
__device__ __forceinline__ unsigned int pk(float a, float b) {
    return ((unsigned int)f2b(a)) | (((unsigned int)f2b(b)) << 16);
}

// ---------------------------------------------------------------------------
// prep_k: fused one-time prep.
//   blocks 0..5   : weight -> split bf16 (hi + residual lo), B-frag order
//   block  6      : out[g] = fcb; gcnt = 0
//   blocks 7..    : x (fp32) -> bf16
// ---------------------------------------------------------------------------
__global__ __launch_bounds__(256) void prep_k(const float* __restrict__ w0,
                                              const float* __restrict__ w1,
                                              const float* __restrict__ w2,
                                              const float* __restrict__ w3,
                                              const float* __restrict__ w4,
                                              const float* __restrict__ w5,
                                              unsigned short* __restrict__ wf,
                                              const float* __restrict__ x,
                                              unsigned short* __restrict__ xb,
                                              int* __restrict__ gcnt,
                                              const float* __restrict__ fcb,
                                              float* __restrict__ outp) {
    int bid = blockIdx.x;
    int tid = threadIdx.x;
    if (bid < 6) {
        const float* ws[6] = {w0, w1, w2, w3, w4, w5};
        const float* w = ws[bid];
        unsigned short* o = wf + bid * 8192;
        for (int i = tid; i < 4096; i += 256) {
            int j = i & 7;
            int quad = (i >> 3) & 3;
            int n = (i >> 5) & 63;
            int kb = i >> 11;
            int k = kb * 32 + quad * 8 + j;
            float wv = w[k * 64 + n];
            unsigned short hi = f2b(wv);
            o[i] = hi;
            o[i + 4096] = f2b(wv - b2f(hi));
        }
    } else if (bid == 6) {
        if (tid < NG) outp[tid] = fcb[0];
        for (int i = tid; i < NBKT; i += 256) gcnt[i] = 0;
    } else {
        int i = (bid - 7) * 256 + tid;
        if (i < NN * 16) {
            float4 v = reinterpret_cast<const float4*>(x)[i];
            ushort4 o;
            o.x = f2b(v.x); o.y = f2b(v.y); o.z = f2b(v.z); o.w = f2b(v.w);
            reinterpret_cast<ushort4*>(xb)[i] = o;
        }
    }
}

// ---------------------------------------------------------------------------
// pscat: edges -> bucket-major packed pairs (one global pass, LDS staged).
// pairs packed: src (17 bits) | local-dst (8 bits) << 17.
// ---------------------------------------------------------------------------
__global__ __launch_bounds__(256) void pscat_k(const int* __restrict__ ei,
                                               int* __restrict__ gcnt,
                                               int* __restrict__ pairs) {
    __shared__ int lc[NBKT];
    __shared__ int gb[NBKT];
    __shared__ int pe[EPB];
    __shared__ unsigned short pb[EPB];
    int tid = threadIdx.x;
    for (int i = tid; i < NBKT; i += 256) lc[i] = 0;
    __syncthreads();
    int base = blockIdx.x * EPB;
    int n = min(base + EPB, NE) - base;
    for (int t = tid; t < n; t += 256) {
        int src = ei[base + t];
        int dst = ei[NE + base + t];
        int b = dst >> BKT_SHIFT;
        pe[t] = src | ((dst & 255) << 17);
        pb[t] = (unsigned short)b;
        atomicAdd(&lc[b], 1);
    }
    __syncthreads();
    for (int i = tid; i < NBKT; i += 256) {
        int c = lc[i];
        gb[i] = c ? atomicAdd(&gcnt[i], c) : 0;
    }
    __syncthreads();
    for (int i = tid; i < NBKT; i += 256) lc[i] = 0;
    __syncthreads();
    for (int t = tid; t < n; t += 256) {
        int b = pb[t];
        int pos = gb[b] + atomicAdd(&lc[b], 1);
        if (pos < CAP) pairs[(size_t)b * CAP + pos] = pe[t];
    }
}

// ---------------------------------------------------------------------------
// bfill: bucket pairs -> rowptr + csr_src, block-local prefix over gcnt.
// ---------------------------------------------------------------------------
__global__ __launch_bounds__(256) void bfill_k(const int* __restrict__ pairs,
                                               const int* __restrict__ gcnt,
                                               int* __restrict__ rowptr,
                                               int* __restrict__ csr_src) {
    __shared__ int ldeg[256];
    __shared__ int sh[256];
    __shared__ int lcur[256];
    __shared__ int redsh[4];
    int b = blockIdx.x;
    int t = threadIdx.x;
    int part = 0;
    for (int i = t; i < NBKT; i += 256)
        if (i < b) part += min(gcnt[i], CAP);
#pragma unroll
    for (int off = 32; off > 0; off >>= 1) part += __shfl_down(part, off, 64);
    if ((t & 63) == 0) redsh[t >> 6] = part;
    ldeg[t] = 0;
    __syncthreads();
    int cbeg = redsh[0] + redsh[1] + redsh[2] + redsh[3];
    int pcnt = min(gcnt[b], CAP);
    const int* pw = pairs + (size_t)b * CAP;
    for (int i = t; i < pcnt; i += 256)
        atomicAdd(&ldeg[(pw[i] >> 17) & 255], 1);
    __syncthreads();
    int v = ldeg[t];
    sh[t] = v;
    __syncthreads();
    for (int off = 1; off < 256; off <<= 1) {
        int u = (t >= off) ? sh[t - off] : 0;
        __syncthreads();
        sh[t] += u;
        __syncthreads();
    }
    int lexcl = sh[t] - v;
    int node = (b << BKT_SHIFT) + t;
    if (node < NN) {
        rowptr[node] = cbeg + lexcl;
        if (node == NN - 1) rowptr[NN] = cbeg + lexcl + v;
    }
    lcur[t] = lexcl;
    __syncthreads();
    for (int i = t; i < pcnt; i += 256) {
        int p = pw[i];
        int pos = atomicAdd(&lcur[(p >> 17) & 255], 1);
        csr_src[cbeg + pos] = p & 0x1FFFF;
    }
}

// ---------------------------------------------------------------------------
// Fused GIN layer: gather (8 nodes/wave, z -> LDS) + split-bf16 MFMA MLP on
// the 32-row tile. Round-15 change: full edge batches (cnt==8, the common
// case at mean deg 16) use a compile-time-unrolled 8-deep load pipeline --
// 8 independent uint4 loads in flight per lane instead of 2.
// ---------------------------------------------------------------------------
__global__ __launch_bounds__(256) void gin_k(
    const uint4* __restrict__ hb4,     // prev h (bf16): gather + self source
    const float4* __restrict__ selff,  // fp32 self (layer 0) or null
    const int* __restrict__ rowptr,
    const int* __restrict__ csr_src,
    const unsigned short* __restrict__ wf1, const float* __restrict__ b1,
    const unsigned short* __restrict__ wf2, const float* __restrict__ b2,
    unsigned short* __restrict__ houtb, int relu_out, int pool_mode,
    const int* __restrict__ batch, const float* __restrict__ fcw,
    float* __restrict__ outp) {
    __shared__ unsigned short zl[32 * 72];   // z tile (bf16)
    __shared__ unsigned short hlh[32 * 72];  // h1 hi
    __shared__ unsigned short hll[32 * 72];  // h1 lo
    int tid = threadIdx.x;
    int lane = tid & 63;
    int wv = tid >> 6;
    int base = blockIdx.x * 32;

    // ---- Phase A: gather + self -> zl (NN == 3125*32, all nodes valid) ----
    {
        int nl = lane >> 3;  // node slot within wave (0..7)
        int c = lane & 7;    // 16 B chunk within row (0..7)
        int r = wv * 8 + nl; // local row 0..31
        int node = base + r;
        int beg = rowptr[node];
        int deg = rowptr[node + 1] - beg;
        float a0 = 0, a1 = 0, a2 = 0, a3 = 0, a4 = 0, a5 = 0, a6 = 0, a7 = 0;
        int nb = (deg + 7) >> 3;
        int idx = (c < deg) ? csr_src[beg + c] : 0;
        int gbase = nl << 3;
        for (int b = 0; b < nb; ++b) {
            int nj = ((b + 1) << 3) + c;
            int nextIdx = (b + 1 < nb && nj < deg) ? csr_src[beg + nj] : 0;
            int cnt = min(8, deg - (b << 3));
            if (cnt == 8) {
                // full batch: 8 independent loads in flight per lane
                int s0 = __shfl(idx, gbase + 0, 64);
                int s1 = __shfl(idx, gbase + 1, 64);
                int s2 = __shfl(idx, gbase + 2, 64);
                int s3 = __shfl(idx, gbase + 3, 64);
                int s4 = __shfl(idx, gbase + 4, 64);
                int s5 = __shfl(idx, gbase + 5, 64);
                int s6 = __shfl(idx, gbase + 6, 64);
                int s7 = __shfl(idx, gbase + 7, 64);
                uint4 v0 = hb4[s0 * 8 + c];
                uint4 v1 = hb4[s1 * 8 + c];
                uint4 v2 = hb4[s2 * 8 + c];
                uint4 v3 = hb4[s3 * 8 + c];
                uint4 v4 = hb4[s4 * 8 + c];
                uint4 v5 = hb4[s5 * 8 + c];
                uint4 v6 = hb4[s6 * 8 + c];
                uint4 v7 = hb4[s7 * 8 + c];
                a0 += lo16(v0.x); a1 += hi16(v0.x);
                a2 += lo16(v0.y); a3 += hi16(v0.y);
                a4 += lo16(v0.z); a5 += hi16(v0.z);
                a6 += lo16(v0.w); a7 += hi16(v0.w);
                a0 += lo16(v1.x); a1 += hi16(v1.x);
                a2 += lo16(v1.y); a3 += hi16(v1.y);
                a4 += lo16(v1.z); a5 += hi16(v1.z);
                a6 += lo16(v1.w); a7 += hi16(v1.w);
                a0 += lo16(v2.x); a1 += hi16(v2.x);
                a2 += lo16(v2.y); a3 += hi16(v2.y);
                a4 += lo16(v2.z); a5 += hi16(v2.z);
                a6 += lo16(v2.w); a7 += hi16(v2.w);
                a0 += lo16(v3.x); a1 += hi16(v3.x);
                a2 += lo16(v3.y); a3 += hi16(v3.y);
                a4 += lo16(v3.z); a5 += hi16(v3.z);
                a6 += lo16(v3.w); a7 += hi16(v3.w);
                a0 += lo16(v4.x); a1 += hi16(v4.x);
                a2 += lo16(v4.y); a3 += hi16(v4.y);
                a4 += lo16(v4.z); a5 += hi16(v4.z);
                a6 += lo16(v4.w); a7 += hi16(v4.w);
                a0 += lo16(v5.x); a1 += hi16(v5.x);
                a2 += lo16(v5.y); a3 += hi16(v5.y);
                a4 += lo16(v5.z); a5 += hi16(v5.z);
                a6 += lo16(v5.w); a7 += hi16(v5.w);
                a0 += lo16(v6.x); a1 += hi16(v6.x);
                a2 += lo16(v6.y); a3 += hi16(v6.y);
                a4 += lo16(v6.z); a5 += hi16(v6.z);
                a6 += lo16(v6.w); a7 += hi16(v6.w);
                a0 += lo16(v7.x); a1 += hi16(v7.x);
                a2 += lo16(v7.y); a3 += hi16(v7.y);
                a4 += lo16(v7.z); a5 += hi16(v7.z);
                a6 += lo16(v7.w); a7 += hi16(v7.w);
            } else {
                for (int e = 0; e < cnt; ++e) {
                    int s = __shfl(idx, gbase + e, 64);
                    uint4 v = hb4[s * 8 + c];
                    a0 += lo16(v.x); a1 += hi16(v.x);
                    a2 += lo16(v.y); a3 += hi16(v.y);
                    a4 += lo16(v.z); a5 += hi16(v.z);
                    a6 += lo16(v.w); a7 += hi16(v.w);
                }
            }
            idx = nextIdx;
        }
        if (selff) {
            float4 s0 = selff[(size_t)node * 16 + 2 * c];
            float4 s1 = selff[(size_t)node * 16 + 2 * c + 1];
            a0 += s0.x; a1 += s0.y; a2 += s0.z; a3 += s0.w;
            a4 += s1.x; a5 += s1.y; a6 += s1.z; a7 += s1.w;
        } else {
            uint4 sv = hb4[node * 8 + c];
            a0 += lo16(sv.x); a1 += hi16(sv.x);
            a2 += lo16(sv.y); a3 += hi16(sv.y);
            a4 += lo16(sv.z); a5 += hi16(sv.z);
            a6 += lo16(sv.w); a7 += hi16(sv.w);
        }
        uint4 o;
        o.x = pk(a0, a1); o.y = pk(a2, a3); o.z = pk(a4, a5); o.w = pk(a6, a7);
        *reinterpret_cast<uint4*>(&zl[r * 72 + c * 8]) = o;
    }
    __syncthreads();

    // ---- Phase B: MLP on the 32-row tile ----
    int m = lane & 15;
    int quad = lane >> 4;
    int mt = wv >> 1;  // row half (rows mt*16 + 0..15)
    int nh = wv & 1;   // col half (n-tiles nh*2, nh*2+1)
    int lrow = mt * 16 + m;

    bf16x8 a0 = *reinterpret_cast<const bf16x8*>(&zl[lrow * 72 + quad * 8]);
    bf16x8 a1 = *reinterpret_cast<const bf16x8*>(&zl[lrow * 72 + 32 + quad * 8]);
    const bf16x8* wh1 = reinterpret_cast<const bf16x8*>(wf1);
    const bf16x8* wl1 = reinterpret_cast<const bf16x8*>(wf1 + 4096);
    f32x4 acc[2];
#pragma unroll
    for (int nt2 = 0; nt2 < 2; ++nt2) {
        int n = (nh * 2 + nt2) * 16 + m;
        bf16x8 bh0 = wh1[(0 * 64 + n) * 4 + quad];
        bf16x8 bh1 = wh1[(1 * 64 + n) * 4 + quad];
        bf16x8 bl0 = wl1[(0 * 64 + n) * 4 + quad];
        bf16x8 bl1 = wl1[(1 * 64 + n) * 4 + quad];
        f32x4 c = {0.f, 0.f, 0.f, 0.f};
        c = __builtin_amdgcn_mfma_f32_16x16x32_bf16(a0, bh0, c, 0, 0, 0);
        c = __builtin_amdgcn_mfma_f32_16x16x32_bf16(a1, bh1, c, 0, 0, 0);
        c = __builtin_amdgcn_mfma_f32_16x16x32_bf16(a0, bl0, c, 0, 0, 0);
        c = __builtin_amdgcn_mfma_f32_16x16x32_bf16(a1, bl1, c, 0, 0, 0);
        acc[nt2] = c;
    }
    // h1 = ReLU(acc + b1) -> split bf16 into LDS (C-layout scatter)
#pragma unroll
    for (int nt2 = 0; nt2 < 2; ++nt2) {
        int col = (nh * 2 + nt2) * 16 + m;
        float bb = b1[col];
#pragma unroll
        for (int rr = 0; rr < 4; ++rr) {
            float v = fmaxf(acc[nt2][rr] + bb, 0.f);
            unsigned short hi = f2b(v);
            hlh[(mt * 16 + quad * 4 + rr) * 72 + col] = hi;
            hll[(mt * 16 + quad * 4 + rr) * 72 + col] = f2b(v - b2f(hi));
        }
    }
    __syncthreads();

    // GEMM2: A (hi+lo) from LDS
    bf16x8 ch0 = *reinterpret_cast<const bf16x8*>(&hlh[lrow * 72 + quad * 8]);
    bf16x8 ch1 = *reinterpret_cast<const bf16x8*>(&hlh[lrow * 72 + 32 + quad * 8]);
    bf16x8 cl0 = *reinterpret_cast<const bf16x8*>(&hll[lrow * 72 + quad * 8]);
    bf16x8 cl1 = *reinterpret_cast<const bf16x8*>(&hll[lrow * 72 + 32 + quad * 8]);
    const bf16x8* wh2 = reinterpret_cast<const bf16x8*>(wf2);
    const bf16x8* wl2 = reinterpret_cast<const bf16x8*>(wf2 + 4096);
#pragma unroll
    for (int nt2 = 0; nt2 < 2; ++nt2) {
        int n = (nh * 2 + nt2) * 16 + m;
        bf16x8 bh0 = wh2[(0 * 64 + n) * 4 + quad];
        bf16x8 bh1 = wh2[(1 * 64 + n) * 4 + quad];
        bf16x8 bl0 = wl2[(0 * 64 + n) * 4 + quad];
        bf16x8 bl1 = wl2[(1 * 64 + n) * 4 + quad];
        f32x4 c = {0.f, 0.f, 0.f, 0.f};
        c = __builtin_amdgcn_mfma_f32_16x16x32_bf16(ch0, bh0, c, 0, 0, 0);
        c = __builtin_amdgcn_mfma_f32_16x16x32_bf16(ch1, bh1, c, 0, 0, 0);
        c = __builtin_amdgcn_mfma_f32_16x16x32_bf16(ch0, bl0, c, 0, 0, 0);
        c = __builtin_amdgcn_mfma_f32_16x16x32_bf16(ch1, bl1, c, 0, 0, 0);
        c = __builtin_amdgcn_mfma_f32_16x16x32_bf16(cl0, bh0, c, 0, 0, 0);
        c = __builtin_amdgcn_mfma_f32_16x16x32_bf16(cl1, bh1, c, 0, 0, 0);
        acc[nt2] = c;
    }
    __syncthreads();  // all GEMM2 LDS reads done; hlh/hll reusable

    if (pool_mode) {
        // fused global_add_pool + FC
        float psum[4] = {0.f, 0.f, 0.f, 0.f};
#pragma unroll
        for (int nt2 = 0; nt2 < 2; ++nt2) {
            int col = (nh * 2 + nt2) * 16 + m;
            float fw = fcw[col];
            float bb = b2[col];
#pragma unroll
            for (int rr = 0; rr < 4; ++rr) psum[rr] += (acc[nt2][rr] + bb) * fw;
        }
#pragma unroll
        for (int rr = 0; rr < 4; ++rr)
#pragma unroll
            for (int off = 8; off > 0; off >>= 1)
                psum[rr] += __shfl_down(psum[rr], off, 64);
        float* gsum = reinterpret_cast<float*>(hlh);
        gsum[tid] = 0.f;  // tid 0..255 == graph ids
        __syncthreads();
        if (m == 0) {
#pragma unroll
            for (int rr = 0; rr < 4; ++rr) {
                int row = base + mt * 16 + quad * 4 + rr;
                atomicAdd(&gsum[batch[row]], psum[rr]);
            }
        }
        __syncthreads();
        float v = gsum[tid];
        if (v != 0.f) unsafeAtomicAdd(&outp[tid], v);
        return;
    }

    // epilogue: bias (+relu) -> LDS bf16, then coalesced stores
#pragma unroll
    for (int nt2 = 0; nt2 < 2; ++nt2) {
        int col = (nh * 2 + nt2) * 16 + m;
        float bb = b2[col];
#pragma unroll
        for (int rr = 0; rr < 4; ++rr) {
            float v = acc[nt2][rr] + bb;
            if (relu_out) v = fmaxf(v, 0.f);
            hlh[(mt * 16 + quad * 4 + rr) * 72 + col] = f2b(v);
        }
    }
    __syncthreads();
    {
        int row = tid >> 3;  // 0..31
        int ch = tid & 7;
        uint4 v = *reinterpret_cast<const uint4*>(&hlh[row * 72 + ch * 8]);
        *reinterpret_cast<uint4*>(houtb + (size_t)(base + row) * 64 + ch * 8) = v;
    }
}

extern "C" void kernel_launch(void* const* d_in, const int* in_sizes, int n_in,
                              void* d_out, int out_size, void* d_ws, size_t ws_size,
                              hipStream_t stream) {
    const float* x = (const float*)d_in[0];
    const int* ei = (const int*)d_in[1];     // [2, E] flat
    const int* batch = (const int*)d_in[2];  // [N], sorted
    const float* w[3][4];
    for (int l = 0; l < 3; ++l)
        for (int i = 0; i < 4; ++i) w[l][i] = (const float*)d_in[3 + l * 4 + i];
    const float* fcw = (const float*)d_in[15];
    const float* fcb = (const float*)d_in[16];
    float* out = (float*)d_out;

    // workspace layout (~58 MB)
    int* pairs = (int*)d_ws;                               // NBKT*CAP ints (25.6 MB)
    unsigned short* H1 = (unsigned short*)d_ws;            // bf16 h, aliases pairs
    unsigned short* H0 = (unsigned short*)((char*)d_ws + (size_t)NBKT * CAP * 4);  // 12.8 MB
    int* rowptr = (int*)(H0 + (size_t)NN * DD);            // N+1
    int* csr_src = rowptr + NN + 1;                        // NE (6.4 MB)
    int* gcnt = csr_src + NE;                              // NBKT
    unsigned short* wf = (unsigned short*)(gcnt + NBKT);   // 6*8192 bf16 (96 KB)

    // one-time prep: weights->split-bf16 frags, x->bf16 (H0), gcnt=0, out=fcb
    prep_k<<<7 + (NN * 16 + 255) / 256, 256, 0, stream>>>(
        w[0][0], w[0][2], w[1][0], w[1][2], w[2][0], w[2][2], wf, x, H0, gcnt, fcb,
        out);

    // CSR build (pairs consumed by bfill before H1 is first written)
    pscat_k<<<NEB, 256, 0, stream>>>(ei, gcnt, pairs);
    bfill_k<<<NBKT, 256, 0, stream>>>(pairs, gcnt, rowptr, csr_src);

    dim3 lgrid(NN / 32);
    // L0: read H0(=xb)+x, write H1
    gin_k<<<lgrid, 256, 0, stream>>>((const uint4*)H0, (const float4*)x, rowptr,
                                     csr_src, wf + 0 * 8192, w[0][1], wf + 1 * 8192,
                                     w[0][3], H1, 1, 0, nullptr, nullptr, nullptr);
    // L1: read H1, write H0
    gin_k<<<lgrid, 256, 0, stream>>>((const uint4*)H1, nullptr, rowptr, csr_src,
                                     wf + 2 * 8192, w[1][1], wf + 3 * 8192, w[1][3],
                                     H0, 1, 0, nullptr, nullptr, nullptr);
    // L2: read H0, fused pool + FC
    gin_k<<<lgrid, 256, 0, stream>>>((const uint4*)H0, nullptr, rowptr, csr_src,
                                     wf + 4 * 8192, w[2][1], wf + 5 * 8192, w[2][3],
                                     nullptr, 0, 1, batch, fcw, out);
}

// Round 16
// 276.437 us; speedup vs baseline: 1.0491x; 1.0491x over previous
//
#include <hip/hip_runtime.h>

constexpr int NN = 100000;   // nodes (= 3125 * 32 exactly)
constexpr int NE = 1600000;  // edges
constexpr int DD = 64;       // channels
constexpr int NG = 256;      // graphs

constexpr int BKT_SHIFT = 8;                   // 256 nodes per bucket
constexpr int NBKT = (NN + 255) >> BKT_SHIFT;  // 391 buckets
constexpr int EPB = 4096;                      // edges per block (build kernels)
constexpr int NEB = (NE + EPB - 1) / EPB;      // 391 blocks
constexpr int CAP = 16384;                     // pair window per bucket (mean 4092)

using bf16x8 = __attribute__((ext_vector_type(8))) short;
using f32x4 = __attribute__((ext_vector_type(4))) float;

// ---------------------------------------------------------------------------
// bf16 helpers (manual, RNE)
// ---------------------------------------------------------------------------
__device__ __forceinline__ float b2f(unsigned short u) {
    union { unsigned int u; float f; } c;
    c.u = ((unsigned int)u) << 16;
    return c.f;
}
__device__ __forceinline__ unsigned short f2b(float f) {
    union { float f; unsigned int u; } c;
    c.f = f;
    unsigned int u = c.u + 0x7fff + ((c.u >> 16) & 1);
    return (unsigned short)(u >> 16);
}
__device__ __forceinline__ float lo16(unsigned int u) {
    union { unsigned int u; float f; } c;
    c.u = u << 16;
    return c.f;
}
__device__ __forceinline__ float hi16(unsigned int u) {
    union { unsigned int u; float f; } c;
    c.u = u & 0xffff0000u;
    return c.f;
}
__device__ __forceinline__ unsigned int pk(float a, float b) {
    return ((unsigned int)f2b(a)) | (((unsigned int)f2b(b)) << 16);
}

// ---------------------------------------------------------------------------
// prep_k: fused one-time prep.
//   blocks 0..5   : weight -> split bf16 (hi + residual lo), B-frag order
//   block  6      : out[g] = fcb; gcnt = 0
//   blocks 7..    : x (fp32) -> bf16
// ---------------------------------------------------------------------------
__global__ __launch_bounds__(256) void prep_k(const float* __restrict__ w0,
                                              const float* __restrict__ w1,
                                              const float* __restrict__ w2,
                                              const float* __restrict__ w3,
                                              const float* __restrict__ w4,
                                              const float* __restrict__ w5,
                                              unsigned short* __restrict__ wf,
                                              const float* __restrict__ x,
                                              unsigned short* __restrict__ xb,
                                              int* __restrict__ gcnt,
                                              const float* __restrict__ fcb,
                                              float* __restrict__ outp) {
    int bid = blockIdx.x;
    int tid = threadIdx.x;
    if (bid < 6) {
        const float* ws[6] = {w0, w1, w2, w3, w4, w5};
        const float* w = ws[bid];
        unsigned short* o = wf + bid * 8192;
        for (int i = tid; i < 4096; i += 256) {
            int j = i & 7;
            int quad = (i >> 3) & 3;
            int n = (i >> 5) & 63;
            int kb = i >> 11;
            int k = kb * 32 + quad * 8 + j;
            float wv = w[k * 64 + n];
            unsigned short hi = f2b(wv);
            o[i] = hi;
            o[i + 4096] = f2b(wv - b2f(hi));
        }
    } else if (bid == 6) {
        if (tid < NG) outp[tid] = fcb[0];
        for (int i = tid; i < NBKT; i += 256) gcnt[i] = 0;
    } else {
        int i = (bid - 7) * 256 + tid;
        if (i < NN * 16) {
            float4 v = reinterpret_cast<const float4*>(x)[i];
            ushort4 o;
            o.x = f2b(v.x); o.y = f2b(v.y); o.z = f2b(v.z); o.w = f2b(v.w);
            reinterpret_cast<ushort4*>(xb)[i] = o;
        }
    }
}

// ---------------------------------------------------------------------------
// pscat: edges -> bucket-major packed pairs (one global pass, LDS staged).
// pairs packed: src (17 bits) | local-dst (8 bits) << 17.
// ---------------------------------------------------------------------------
__global__ __launch_bounds__(256) void pscat_k(const int* __restrict__ ei,
                                               int* __restrict__ gcnt,
                                               int* __restrict__ pairs) {
    __shared__ int lc[NBKT];
    __shared__ int gb[NBKT];
    __shared__ int pe[EPB];
    __shared__ unsigned short pb[EPB];
    int tid = threadIdx.x;
    for (int i = tid; i < NBKT; i += 256) lc[i] = 0;
    __syncthreads();
    int base = blockIdx.x * EPB;
    int n = min(base + EPB, NE) - base;
    for (int t = tid; t < n; t += 256) {
        int src = ei[base + t];
        int dst = ei[NE + base + t];
        int b = dst >> BKT_SHIFT;
        pe[t] = src | ((dst & 255) << 17);
        pb[t] = (unsigned short)b;
        atomicAdd(&lc[b], 1);
    }
    __syncthreads();
    for (int i = tid; i < NBKT; i += 256) {
        int c = lc[i];
        gb[i] = c ? atomicAdd(&gcnt[i], c) : 0;
    }
    __syncthreads();
    for (int i = tid; i < NBKT; i += 256) lc[i] = 0;
    __syncthreads();
    for (int t = tid; t < n; t += 256) {
        int b = pb[t];
        int pos = gb[b] + atomicAdd(&lc[b], 1);
        if (pos < CAP) pairs[(size_t)b * CAP + pos] = pe[t];
    }
}

// ---------------------------------------------------------------------------
// bfill: bucket pairs -> rowptr + csr_src, block-local prefix over gcnt.
// ---------------------------------------------------------------------------
__global__ __launch_bounds__(256) void bfill_k(const int* __restrict__ pairs,
                                               const int* __restrict__ gcnt,
                                               int* __restrict__ rowptr,
                                               int* __restrict__ csr_src) {
    __shared__ int ldeg[256];
    __shared__ int sh[256];
    __shared__ int lcur[256];
    __shared__ int redsh[4];
    int b = blockIdx.x;
    int t = threadIdx.x;
    int part = 0;
    for (int i = t; i < NBKT; i += 256)
        if (i < b) part += min(gcnt[i], CAP);
#pragma unroll
    for (int off = 32; off > 0; off >>= 1) part += __shfl_down(part, off, 64);
    if ((t & 63) == 0) redsh[t >> 6] = part;
    ldeg[t] = 0;
    __syncthreads();
    int cbeg = redsh[0] + redsh[1] + redsh[2] + redsh[3];
    int pcnt = min(gcnt[b], CAP);
    const int* pw = pairs + (size_t)b * CAP;
    for (int i = t; i < pcnt; i += 256)
        atomicAdd(&ldeg[(pw[i] >> 17) & 255], 1);
    __syncthreads();
    int v = ldeg[t];
    sh[t] = v;
    __syncthreads();
    for (int off = 1; off < 256; off <<= 1) {
        int u = (t >= off) ? sh[t - off] : 0;
        __syncthreads();
        sh[t] += u;
        __syncthreads();
    }
    int lexcl = sh[t] - v;
    int node = (b << BKT_SHIFT) + t;
    if (node < NN) {
        rowptr[node] = cbeg + lexcl;
        if (node == NN - 1) rowptr[NN] = cbeg + lexcl + v;
    }
    lcur[t] = lexcl;
    __syncthreads();
    for (int i = t; i < pcnt; i += 256) {
        int p = pw[i];
        int pos = atomicAdd(&lcur[(p >> 17) & 255], 1);
        csr_src[cbeg + pos] = p & 0x1FFFF;
    }
}

// ---------------------------------------------------------------------------
// Fused GIN layer: gather (8 nodes/wave, z -> LDS) + split-bf16 MFMA MLP on
// the 32-row tile. Gather loop is the round-14 2-deep ping-pong: VGPR 28 ->
// ~18 waves/CU; TLP (not per-lane ILP) is what hides the random-fetch
// latency here [round-15 counter-evidence: depth-8 raised VGPR to 48,
// dropped occupancy 58->40% and regressed 46->51.5 us].
// ---------------------------------------------------------------------------
__global__ __launch_bounds__(256) void gin_k(
    const uint4* __restrict__ hb4,     // prev h (bf16): gather + self source
    const float4* __restrict__ selff,  // fp32 self (layer 0) or null
    const int* __restrict__ rowptr,
    const int* __restrict__ csr_src,
    const unsigned short* __restrict__ wf1, const float* __restrict__ b1,
    const unsigned short* __restrict__ wf2, const float* __restrict__ b2,
    unsigned short* __restrict__ houtb, int relu_out, int pool_mode,
    const int* __restrict__ batch, const float* __restrict__ fcw,
    float* __restrict__ outp) {
    __shared__ unsigned short zl[32 * 72];   // z tile (bf16)
    __shared__ unsigned short hlh[32 * 72];  // h1 hi
    __shared__ unsigned short hll[32 * 72];  // h1 lo
    int tid = threadIdx.x;
    int lane = tid & 63;
    int wv = tid >> 6;
    int base = blockIdx.x * 32;

    // ---- Phase A: gather + self -> zl (NN == 3125*32, all nodes valid) ----
    {
        int nl = lane >> 3;  // node slot within wave (0..7)
        int c = lane & 7;    // 16 B chunk within row (0..7)
        int r = wv * 8 + nl; // local row 0..31
        int node = base + r;
        int beg = rowptr[node];
        int deg = rowptr[node + 1] - beg;
        float a0 = 0, a1 = 0, a2 = 0, a3 = 0, a4 = 0, a5 = 0, a6 = 0, a7 = 0;
        int nb = (deg + 7) >> 3;
        int idx = (c < deg) ? csr_src[beg + c] : 0;
        int gbase = nl << 3;
        for (int b = 0; b < nb; ++b) {
            int nj = ((b + 1) << 3) + c;
            int nextIdx = (b + 1 < nb && nj < deg) ? csr_src[beg + nj] : 0;
            int cnt = min(8, deg - (b << 3));
            int s0 = __shfl(idx, gbase, 64);
            uint4 v0 = hb4[s0 * 8 + c];
            for (int e = 1; e < cnt; ++e) {
                int s1 = __shfl(idx, gbase + e, 64);
                uint4 v1 = hb4[s1 * 8 + c];  // issue before consuming v0
                a0 += lo16(v0.x); a1 += hi16(v0.x);
                a2 += lo16(v0.y); a3 += hi16(v0.y);
                a4 += lo16(v0.z); a5 += hi16(v0.z);
                a6 += lo16(v0.w); a7 += hi16(v0.w);
                v0 = v1;
            }
            a0 += lo16(v0.x); a1 += hi16(v0.x);
            a2 += lo16(v0.y); a3 += hi16(v0.y);
            a4 += lo16(v0.z); a5 += hi16(v0.z);
            a6 += lo16(v0.w); a7 += hi16(v0.w);
            idx = nextIdx;
        }
        if (selff) {
            float4 s0 = selff[(size_t)node * 16 + 2 * c];
            float4 s1 = selff[(size_t)node * 16 + 2 * c + 1];
            a0 += s0.x; a1 += s0.y; a2 += s0.z; a3 += s0.w;
            a4 += s1.x; a5 += s1.y; a6 += s1.z; a7 += s1.w;
        } else {
            uint4 sv = hb4[node * 8 + c];
            a0 += lo16(sv.x); a1 += hi16(sv.x);
            a2 += lo16(sv.y); a3 += hi16(sv.y);
            a4 += lo16(sv.z); a5 += hi16(sv.z);
            a6 += lo16(sv.w); a7 += hi16(sv.w);
        }
        uint4 o;
        o.x = pk(a0, a1); o.y = pk(a2, a3); o.z = pk(a4, a5); o.w = pk(a6, a7);
        *reinterpret_cast<uint4*>(&zl[r * 72 + c * 8]) = o;
    }
    __syncthreads();

    // ---- Phase B: MLP on the 32-row tile ----
    int m = lane & 15;
    int quad = lane >> 4;
    int mt = wv >> 1;  // row half (rows mt*16 + 0..15)
    int nh = wv & 1;   // col half (n-tiles nh*2, nh*2+1)
    int lrow = mt * 16 + m;

    bf16x8 a0 = *reinterpret_cast<const bf16x8*>(&zl[lrow * 72 + quad * 8]);
    bf16x8 a1 = *reinterpret_cast<const bf16x8*>(&zl[lrow * 72 + 32 + quad * 8]);
    const bf16x8* wh1 = reinterpret_cast<const bf16x8*>(wf1);
    const bf16x8* wl1 = reinterpret_cast<const bf16x8*>(wf1 + 4096);
    f32x4 acc[2];
#pragma unroll
    for (int nt2 = 0; nt2 < 2; ++nt2) {
        int n = (nh * 2 + nt2) * 16 + m;
        bf16x8 bh0 = wh1[(0 * 64 + n) * 4 + quad];
        bf16x8 bh1 = wh1[(1 * 64 + n) * 4 + quad];
        bf16x8 bl0 = wl1[(0 * 64 + n) * 4 + quad];
        bf16x8 bl1 = wl1[(1 * 64 + n) * 4 + quad];
        f32x4 c = {0.f, 0.f, 0.f, 0.f};
        c = __builtin_amdgcn_mfma_f32_16x16x32_bf16(a0, bh0, c, 0, 0, 0);
        c = __builtin_amdgcn_mfma_f32_16x16x32_bf16(a1, bh1, c, 0, 0, 0);
        c = __builtin_amdgcn_mfma_f32_16x16x32_bf16(a0, bl0, c, 0, 0, 0);
        c = __builtin_amdgcn_mfma_f32_16x16x32_bf16(a1, bl1, c, 0, 0, 0);
        acc[nt2] = c;
    }
    // h1 = ReLU(acc + b1) -> split bf16 into LDS (C-layout scatter)
#pragma unroll
    for (int nt2 = 0; nt2 < 2; ++nt2) {
        int col = (nh * 2 + nt2) * 16 + m;
        float bb = b1[col];
#pragma unroll
        for (int rr = 0; rr < 4; ++rr) {
            float v = fmaxf(acc[nt2][rr] + bb, 0.f);
            unsigned short hi = f2b(v);
            hlh[(mt * 16 + quad * 4 + rr) * 72 + col] = hi;
            hll[(mt * 16 + quad * 4 + rr) * 72 + col] = f2b(v - b2f(hi));
        }
    }
    __syncthreads();

    // GEMM2: A (hi+lo) from LDS
    bf16x8 ch0 = *reinterpret_cast<const bf16x8*>(&hlh[lrow * 72 + quad * 8]);
    bf16x8 ch1 = *reinterpret_cast<const bf16x8*>(&hlh[lrow * 72 + 32 + quad * 8]);
    bf16x8 cl0 = *reinterpret_cast<const bf16x8*>(&hll[lrow * 72 + quad * 8]);
    bf16x8 cl1 = *reinterpret_cast<const bf16x8*>(&hll[lrow * 72 + 32 + quad * 8]);
    const bf16x8* wh2 = reinterpret_cast<const bf16x8*>(wf2);
    const bf16x8* wl2 = reinterpret_cast<const bf16x8*>(wf2 + 4096);
#pragma unroll
    for (int nt2 = 0; nt2 < 2; ++nt2) {
        int n = (nh * 2 + nt2) * 16 + m;
        bf16x8 bh0 = wh2[(0 * 64 + n) * 4 + quad];
        bf16x8 bh1 = wh2[(1 * 64 + n) * 4 + quad];
        bf16x8 bl0 = wl2[(0 * 64 + n) * 4 + quad];
        bf16x8 bl1 = wl2[(1 * 64 + n) * 4 + quad];
        f32x4 c = {0.f, 0.f, 0.f, 0.f};
        c = __builtin_amdgcn_mfma_f32_16x16x32_bf16(ch0, bh0, c, 0, 0, 0);
        c = __builtin_amdgcn_mfma_f32_16x16x32_bf16(ch1, bh1, c, 0, 0, 0);
        c = __builtin_amdgcn_mfma_f32_16x16x32_bf16(ch0, bl0, c, 0, 0, 0);
        c = __builtin_amdgcn_mfma_f32_16x16x32_bf16(ch1, bl1, c, 0, 0, 0);
        c = __builtin_amdgcn_mfma_f32_16x16x32_bf16(cl0, bh0, c, 0, 0, 0);
        c = __builtin_amdgcn_mfma_f32_16x16x32_bf16(cl1, bh1, c, 0, 0, 0);
        acc[nt2] = c;
    }
    __syncthreads();  // all GEMM2 LDS reads done; hlh/hll reusable

    if (pool_mode) {
        // fused global_add_pool + FC
        float psum[4] = {0.f, 0.f, 0.f, 0.f};
#pragma unroll
        for (int nt2 = 0; nt2 < 2; ++nt2) {
            int col = (nh * 2 + nt2) * 16 + m;
            float fw = fcw[col];
            float bb = b2[col];
#pragma unroll
            for (int rr = 0; rr < 4; ++rr) psum[rr] += (acc[nt2][rr] + bb) * fw;
        }
#pragma unroll
        for (int rr = 0; rr < 4; ++rr)
#pragma unroll
            for (int off = 8; off > 0; off >>= 1)
                psum[rr] += __shfl_down(psum[rr], off, 64);
        float* gsum = reinterpret_cast<float*>(hlh);
        gsum[tid] = 0.f;  // tid 0..255 == graph ids
        __syncthreads();
        if (m == 0) {
#pragma unroll
            for (int rr = 0; rr < 4; ++rr) {
                int row = base + mt * 16 + quad * 4 + rr;
                atomicAdd(&gsum[batch[row]], psum[rr]);
            }
        }
        __syncthreads();
        float v = gsum[tid];
        if (v != 0.f) unsafeAtomicAdd(&outp[tid], v);
        return;
    }

    // epilogue: bias (+relu) -> LDS bf16, then coalesced stores
#pragma unroll
    for (int nt2 = 0; nt2 < 2; ++nt2) {
        int col = (nh * 2 + nt2) * 16 + m;
        float bb = b2[col];
#pragma unroll
        for (int rr = 0; rr < 4; ++rr) {
            float v = acc[nt2][rr] + bb;
            if (relu_out) v = fmaxf(v, 0.f);
            hlh[(mt * 16 + quad * 4 + rr) * 72 + col] = f2b(v);
        }
    }
    __syncthreads();
    {
        int row = tid >> 3;  // 0..31
        int ch = tid & 7;
        uint4 v = *reinterpret_cast<const uint4*>(&hlh[row * 72 + ch * 8]);
        *reinterpret_cast<uint4*>(houtb + (size_t)(base + row) * 64 + ch * 8) = v;
    }
}

extern "C" void kernel_launch(void* const* d_in, const int* in_sizes, int n_in,
                              void* d_out, int out_size, void* d_ws, size_t ws_size,
                              hipStream_t stream) {
    const float* x = (const float*)d_in[0];
    const int* ei = (const int*)d_in[1];     // [2, E] flat
    const int* batch = (const int*)d_in[2];  // [N], sorted
    const float* w[3][4];
    for (int l = 0; l < 3; ++l)
        for (int i = 0; i < 4; ++i) w[l][i] = (const float*)d_in[3 + l * 4 + i];
    const float* fcw = (const float*)d_in[15];
    const float* fcb = (const float*)d_in[16];
    float* out = (float*)d_out;

    // workspace layout (~58 MB)
    int* pairs = (int*)d_ws;                               // NBKT*CAP ints (25.6 MB)
    unsigned short* H1 = (unsigned short*)d_ws;            // bf16 h, aliases pairs
    unsigned short* H0 = (unsigned short*)((char*)d_ws + (size_t)NBKT * CAP * 4);  // 12.8 MB
    int* rowptr = (int*)(H0 + (size_t)NN * DD);            // N+1
    int* csr_src = rowptr + NN + 1;                        // NE (6.4 MB)
    int* gcnt = csr_src + NE;                              // NBKT
    unsigned short* wf = (unsigned short*)(gcnt + NBKT);   // 6*8192 bf16 (96 KB)

    // one-time prep: weights->split-bf16 frags, x->bf16 (H0), gcnt=0, out=fcb
    prep_k<<<7 + (NN * 16 + 255) / 256, 256, 0, stream>>>(
        w[0][0], w[0][2], w[1][0], w[1][2], w[2][0], w[2][2], wf, x, H0, gcnt, fcb,
        out);

    // CSR build (pairs consumed by bfill before H1 is first written)
    pscat_k<<<NEB, 256, 0, stream>>>(ei, gcnt, pairs);
    bfill_k<<<NBKT, 256, 0, stream>>>(pairs, gcnt, rowptr, csr_src);

    dim3 lgrid(NN / 32);
    // L0: read H0(=xb)+x, write H1
    gin_k<<<lgrid, 256, 0, stream>>>((const uint4*)H0, (const float4*)x, rowptr,
                                     csr_src, wf + 0 * 8192, w[0][1], wf + 1 * 8192,
                                     w[0][3], H1, 1, 0, nullptr, nullptr, nullptr);
    // L1: read H1, write H0
    gin_k<<<lgrid, 256, 0, stream>>>((const uint4*)H1, nullptr, rowptr, csr_src,
                                     wf + 2 * 8192, w[1][1], wf + 3 * 8192, w[1][3],
                                     H0, 1, 0, nullptr, nullptr, nullptr);
    // L2: read H0, fused pool + FC
    gin_k<<<lgrid, 256, 0, stream>>>((const uint4*)H0, nullptr, rowptr, csr_src,
                                     wf + 4 * 8192, w[2][1], wf + 5 * 8192, w[2][3],
                                     nullptr, 0, 1, batch, fcw, out);
}